// Round 15
// baseline (117.490 us; speedup 1.0000x reference)
//
#include <hip/hip_runtime.h>
#include <stdint.h>

typedef __attribute__((__ext_vector_type__(8))) __bf16 bf16x8;
typedef __attribute__((__ext_vector_type__(4))) float  f32x4;

// ---- workspace layout (bytes) ----
#define XT_OFF    0ul          // 16*64*64*256 bf16 = 33,554,432
#define WT_OFF    33554432ul   // 36*16384 bf16     =  1,179,648  [tap][s][co][ci64]
#define BEFF_OFF  34734080ul   // 256 f32
#define ZERO_OFF  34737152ul   // 256 B zeros
#define STATS_OFF 34737408ul   // 512 f32 (sum, sumsq per channel)
#define V_OFF     35651584ul   // 16M bf16 = 33,554,432 (v intermediate, NCHW)
#define WS_NEED   (V_OFF + 33554432ul)

__device__ inline void gload_lds16(const void* g, void* l) {
  __builtin_amdgcn_global_load_lds((const __attribute__((address_space(1))) void*)g,
                                   (__attribute__((address_space(3))) void*)l,
                                   16, 0, 0);
}

// K1 (merged): blocks 0..255 = weight reduction; 256..1279 = x transpose.
__global__ void k_prep(const float* __restrict__ w, const float* __restrict__ bias,
                       const float* __restrict__ alpha_p, __bf16* __restrict__ Wt,
                       float* __restrict__ beff, float* __restrict__ zerob,
                       float* __restrict__ statsG,
                       const float* __restrict__ x, __bf16* __restrict__ xT) {
  __shared__ __bf16 lds[64 * 258];
  if (blockIdx.x < 256) {
    const int co = blockIdx.x;
    const int ci = threadIdx.x;   // 256
    float a[9];
#pragma unroll
    for (int t = 0; t < 9; ++t) a[t] = 0.f;
#pragma unroll
    for (int r = 0; r < 2; ++r)
#pragma unroll
      for (int o = 0; o < 8; ++o) {
        const float* p = w + ((size_t)(r * 256 + co) * 2048 + (size_t)(o * 256 + ci)) * 9;
#pragma unroll
        for (int t = 0; t < 9; ++t) a[t] += p[t];
      }
    const float sc = alpha_p[0] * 0.0625f;      // alpha / (NORI*NROT)
    const int s = ci >> 6, cis = ci & 63;
#pragma unroll
    for (int t = 0; t < 9; ++t)
      Wt[(size_t)(t * 4 + s) * 16384 + co * 64 + cis] = (__bf16)(a[t] * sc);
    if (ci == 0) beff[co] = (bias[co] + bias[256 + co]) * 8.0f * sc;
    if (blockIdx.x == 0) {
      statsG[ci] = 0.f; statsG[256 + ci] = 0.f;
      if (ci < 64) zerob[ci] = 0.f;
    }
  } else {
    // ---- x[b][ci][h][w] f32 -> xT[b][h][w][ci] bf16 (LDS-tiled transpose)
    int bh = blockIdx.x - 256;    // 16*64
    int b = bh >> 6, h = bh & 63;
    int t = threadIdx.x;          // 256
    int w2 = t & 63, cg = t >> 6;
    const float* xb = x + ((size_t)b * 16384 + h) * 64;   // + ci*4096 + w
#pragma unroll 4
    for (int cb = 0; cb < 256; cb += 4) {
      int ci = cb + cg;
      lds[w2 * 258 + ci] = (__bf16)xb[(size_t)ci * 4096 + w2];
    }
    __syncthreads();
    const uint32_t* l32 = (const uint32_t*)lds;
    uint32_t* o32 = (uint32_t*)(xT + ((size_t)b * 64 + h) * 64 * 256);
    int c2 = t & 127, wg = t >> 7;              // 2 w per iter
    for (int w0 = 0; w0 < 64; w0 += 2) {
      int ww = w0 + wg;
      o32[ww * 128 + c2] = l32[ww * 129 + c2];
    }
  }
}

// K2: implicit-GEMM conv + residual + fused BN stats.
// R15: R14's 2-blocks/CU (512 blocks x 512 thr, M=256 x N=128, 8 waves 4m x 2n)
// PLUS B double-buffer with counted vmcnt. Enabled by trimming A's column halo
// (cols -1/64 are always zero-pad since blocks span full image width):
// A slab = 6 rows x 64 cols x 64 ci = 49152 B; + 2 x 16384 B slots = 81920 B
// exactly -> still 2 blocks/CU. Edge frags: clamped read + per-lane zero select.
// Phase: compute(p) -> bar -> [stageA] stageB(p+2, slot p&1) -> vmcnt(2) -> bar.
// B(p+1) loads stay in flight across both barriers (T4); vmcnt(0) only at tail.
#define A_BYTES 49152            // 384 pos * 128 B (6 rows x 64 cols)
#define B_BYTES 16384            // 128 co x 64 ci bf16

__global__ __launch_bounds__(512, 4) void k_conv(
    const float* __restrict__ x, const __bf16* __restrict__ xT,
    const __bf16* __restrict__ Wt, const float* __restrict__ beff,
    const __bf16* __restrict__ zerob, float* __restrict__ out,
    float* __restrict__ statsG, __bf16* __restrict__ vout, int use_v16)
{
  __shared__ __align__(16) char lds[A_BYTES + 2 * B_BYTES];   // 81920 B exactly
  const int u    = blockIdx.x;               // 512 blocks
  const int ch   = (u >> 3) & 1;             // co half (pairs share XCD slot u&7)
  const int pairid = (u & 7) | ((u >> 4) << 3);   // 0..255
  const int bb   = pairid >> 4;              // batch
  const int ho0  = (pairid & 15) << 2;       // 4 output rows per block
  const int tid  = threadIdx.x;
  const int lane = tid & 63;
  const int wid  = tid >> 6;                 // 8 waves: 4 (m rows) x 2 (co 64s)
  const int wr   = wid >> 1;                 // image row ho0+wr
  const int wc   = wid & 1;                  // co 64-group within half
  const int l15  = lane & 15;

  f32x4 acc[4][4];
#pragma unroll
  for (int i = 0; i < 4; ++i)
#pragma unroll
    for (int j = 0; j < 4; ++j)
#pragma unroll
      for (int r = 0; r < 4; ++r) acc[i][j][r] = 0.f;

  const char* zb = (const char*)zerob;
  const bf16x8 zfrag = {};

  // hoisted B ds_read byte offsets within a 16KB slot (co_local 0..127)
  int boff[4][2];
#pragma unroll
  for (int j = 0; j < 4; ++j)
#pragma unroll
    for (int kk = 0; kk < 2; ++kk) {
      const int col    = (wc << 6) + (j << 4) + l15;      // 0..127
      const int ci_off = (kk << 5) + ((lane >> 4) << 3);
      boff[j][kk] = ((col << 7) + (ci_off << 1)) ^ ((col & 7) << 4);
    }
  // B stage per-lane source offset within the 16KB half-tile
  const int bl = lane >> 3;
  const int bsrcLane = (bl << 7) + (((lane & 7) ^ (bl & 7)) << 4);

  // ---- stage A slab for ci-block s: slab[r=6][c=64][ci=64] bf16, 128B/pos.
  // 16B-slot swizzle: phys = logical ^ (pos&7); linear dest + inverse-swz src.
  // Cols are image cols 0..63 (halo is implicit zero); rows may be OOB (zerob).
  auto stageA = [&](int s) {
    const int ci0 = s << 6;
#pragma unroll
    for (int t2 = 0; t2 < 6; ++t2) {
      const int t   = wid + (t2 << 3);         // 0..47
      const int chk = (t << 3) + (lane >> 3);  // pos = r*64 + c, 0..383
      const int r  = chk >> 6;
      const int c  = chk & 63;
      const int ir = ho0 - 1 + r;              // image row
      const int k  = (lane & 7) ^ (chk & 7);   // logical 16B slot (8 ci elems)
      const char* src;
      if (ir >= 0 && ir < 64)
        src = (const char*)(xT + ((((size_t)bb << 6) + ir) * 64 + c) * 256 + ci0 + (k << 3));
      else
        src = zb + (k << 4);
      gload_lds16(src, lds + (t << 10));
    }
  };

  // ---- stage B half-tile for flat phase ph into slot si (2 loads per wave)
  auto stageB = [&](int ph, int si) {
    char* buf = lds + A_BYTES + si * B_BYTES;
    const int s2 = ph / 9, tp = ph - s2 * 9;
    const char* wsrc = (const char*)Wt + ((size_t)(tp * 4 + s2) << 15) + (ch << 14) + bsrcLane;
    gload_lds16(wsrc + (wid << 10), buf + (wid << 10));
    gload_lds16(wsrc + ((wid + 8) << 10), buf + ((wid + 8) << 10));
  };

  // prologue: A(0), B(0)->slot0, B(1)->slot1; drain A+B(0), keep B(1) in flight
  stageA(0);
  stageB(0, 0);
  stageB(1, 1);
  asm volatile("s_waitcnt vmcnt(2)" ::: "memory");
  __builtin_amdgcn_s_barrier();
  asm volatile("" ::: "memory");

  int s = 0, tap = 0;
  for (int p = 0; p < 36; ++p) {
    // ---- compute(p): reads A(s) and B slot p&1
    const int dh = (tap >= 6) ? 2 : (tap >= 3 ? 1 : 0);
    const int dw = tap - dh * 3;
    const char* Bb = lds + A_BYTES + (p & 1) * B_BYTES;
    // A col base for frag i: col_i = i*16 + l15 + dw - 1; only i=0 can be -1
    // (dw==0, l15==0) and only i=3 can be 64 (dw==2, l15==15).
    const int bcol = l15 + dw - 1;
    const int c0 = (bcol < 0) ? 0 : bcol;
    const int c3r = bcol + 48;
    const int c3 = (c3r > 63) ? 63 : c3r;
    const int rowb = (wr + dh) << 6;
    const bool oob0 = (dw == 0);
    const bool oob3 = (dw == 2);
    __builtin_amdgcn_s_setprio(1);
#pragma unroll
    for (int kk = 0; kk < 2; ++kk) {
      const int ci_off = (kk << 5) + ((lane >> 4) << 3);
      const int cib2 = ci_off << 1;
      bf16x8 av[4];
      {
        const int col = c0;
        av[0] = *(const bf16x8*)(lds + ((((rowb + col) << 7) + cib2) ^ ((col & 7) << 4)));
      }
#pragma unroll
      for (int i = 1; i < 3; ++i) {
        const int col = bcol + (i << 4);
        av[i] = *(const bf16x8*)(lds + ((((rowb + col) << 7) + cib2) ^ ((col & 7) << 4)));
      }
      {
        const int col = c3;
        av[3] = *(const bf16x8*)(lds + ((((rowb + col) << 7) + cib2) ^ ((col & 7) << 4)));
      }
      if (oob0) av[0] = (l15 == 0) ? zfrag : av[0];
      if (oob3) av[3] = (l15 == 15) ? zfrag : av[3];
#pragma unroll
      for (int j = 0; j < 4; ++j) {
        const bf16x8 bv = *(const bf16x8*)(Bb + boff[j][kk]);
#pragma unroll
        for (int i = 0; i < 4; ++i)
          acc[i][j] = __builtin_amdgcn_mfma_f32_16x16x32_bf16(av[i], bv, acc[i][j], 0, 0, 0);
      }
    }
    __builtin_amdgcn_s_setprio(0);
    asm volatile("" ::: "memory");
    __builtin_amdgcn_s_barrier();              // readers of slot p&1 / A(s) done
    asm volatile("" ::: "memory");

    // ---- issue next stages (A first so vmcnt(2) drains it; B(p+2) newest)
    if (tap == 8 && s < 3) stageA(s + 1);
    if (p + 2 < 36) {
      stageB(p + 2, p & 1);
      asm volatile("s_waitcnt vmcnt(2)" ::: "memory");  // B(p+1)+A landed; B(p+2) flying
    } else if (p + 1 < 36) {
      asm volatile("s_waitcnt vmcnt(0)" ::: "memory");  // tail: B(35) landed
    }
    __builtin_amdgcn_s_barrier();              // publish
    asm volatile("" ::: "memory");

    if (++tap == 9) { tap = 0; ++s; }
  }

  // ---- epilogue: v = x+conv+beff, stats in-reg (f32), bf16 v via per-wave
  // LDS repack -> full-line 16B/lane stores (use_v16), else f32 to out.
  __syncthreads();
  float* lstat = (float*)(lds + A_BYTES);      // 256 floats (B region now free)
  if (tid < 256) lstat[tid] = 0.f;
  __syncthreads();

  char* wreg = lds + wid * 2048;               // per-wave repack (16KB in A region)
  const int wq = lane >> 4;                    // 0..3 (w quad group)
  const int ho = ho0 + wr;
  const int xorco = (l15 & 7) << 4;
#pragma unroll
  for (int j = 0; j < 4; ++j) {
    const int col = (wc << 6) + (j << 4) + l15;         // co_local 0..127
    const int cog = (ch << 7) + col;                    // global co
    const float be = beff[cog];
    const size_t base = ((((size_t)bb << 8) + (size_t)cog) << 12) + (ho << 6);
    float r1 = 0.f, r2 = 0.f;
#pragma unroll
    for (int i = 0; i < 4; ++i) {
      const int w0 = (i << 4) + (wq << 2);
      const float4 xv = *(const float4*)(x + base + w0);
      float4 v;
      v.x = acc[i][j][0] + xv.x + be;
      v.y = acc[i][j][1] + xv.y + be;
      v.z = acc[i][j][2] + xv.z + be;
      v.w = acc[i][j][3] + xv.w + be;
      r1 += v.x + v.y + v.z + v.w;
      r2 += v.x * v.x + v.y * v.y + v.z * v.z + v.w * v.w;
      if (use_v16) {
        union { __bf16 h[4]; uint64_t u64; } pk;
        pk.h[0] = (__bf16)v.x; pk.h[1] = (__bf16)v.y;
        pk.h[2] = (__bf16)v.z; pk.h[3] = (__bf16)v.w;
        const int wa = (l15 << 7) + (i << 5) + (wq << 3);
        *(uint64_t*)(wreg + (wa ^ xorco)) = pk.u64;
      } else {
        *(float4*)(out + base + w0) = v;
      }
    }
    r1 += __shfl_xor(r1, 16); r2 += __shfl_xor(r2, 16);
    r1 += __shfl_xor(r1, 32); r2 += __shfl_xor(r2, 32);
    if (lane < 16) {
      atomicAdd(&lstat[col], r1);
      atomicAdd(&lstat[128 + col], r2);
    }
    if (use_v16) {
      asm volatile("s_waitcnt lgkmcnt(0)" ::: "memory");   // wave's writes visible
#pragma unroll
      for (int t2 = 0; t2 < 2; ++t2) {
        const int co_r = lane >> 2;              // 0..15
        const int chk  = (lane & 3) + (t2 << 2); // 16B chunk = 8 w
        const int ra   = (co_r << 7) + (chk << 4);
        const uint4 pv = *(const uint4*)(wreg + (ra ^ ((co_r & 7) << 4)));
        const int co_g = (ch << 7) + (wc << 6) + (j << 4) + co_r;
        const size_t oi = ((((size_t)bb << 8) + (size_t)co_g) << 12) + (ho << 6) + (chk << 3);
        *(uint4*)(vout + oi) = pv;               // 16B x 4 lanes/co -> 64B lines
      }
      asm volatile("s_waitcnt lgkmcnt(0)" ::: "memory");   // reads done before next j
    }
  }
  __syncthreads();
  if (tid < 256) {
    const int c = tid & 127, part = tid >> 7;
    atomicAdd(&statsG[part * 256 + (ch << 7) + c], lstat[part * 128 + c]);
  }
}

// K3a: BN finalize + apply from bf16 v (NCHW) -> f32 out (grid-stride)
__global__ void k_apply_v16(const __bf16* __restrict__ v, float* __restrict__ out,
                            const float* __restrict__ statsG,
                            const float* __restrict__ gamma,
                            const float* __restrict__ beta) {
  __shared__ float ssc[256], ssh[256];
  const int t = threadIdx.x;    // 256
  {
    const float mean = statsG[t] * (1.f / 65536.f);
    const float var  = statsG[256 + t] * (1.f / 65536.f) - mean * mean;
    const float inv  = rsqrtf(var + 1e-5f);
    const float sc   = gamma[t] * inv;
    ssc[t] = sc;
    ssh[t] = beta[t] - mean * sc;
  }
  __syncthreads();
  const uint4* vp = (const uint4*)v;           // 8 bf16 per uint4
  for (size_t g = (size_t)blockIdx.x * 256 + t; g < 2097152ul; g += (size_t)gridDim.x * 256) {
    const int co = (int)((g >> 9) & 255);      // 512 chunks of 8 per (b,co) plane
    const uint4 pv = vp[g];
    const float sc = ssc[co], sh = ssh[co];
    float4 y0, y1;
    y0.x = __uint_as_float((pv.x & 0xffffu) << 16) * sc + sh;
    y0.y = __uint_as_float(pv.x & 0xffff0000u) * sc + sh;
    y0.z = __uint_as_float((pv.y & 0xffffu) << 16) * sc + sh;
    y0.w = __uint_as_float(pv.y & 0xffff0000u) * sc + sh;
    y1.x = __uint_as_float((pv.z & 0xffffu) << 16) * sc + sh;
    y1.y = __uint_as_float(pv.z & 0xffff0000u) * sc + sh;
    y1.z = __uint_as_float((pv.w & 0xffffu) << 16) * sc + sh;
    y1.w = __uint_as_float(pv.w & 0xffff0000u) * sc + sh;
    float4* op = (float4*)(out + g * 8);
    op[0] = y0;
    op[1] = y1;
  }
}

// K3b: fallback — BN finalize + in-place apply on f32 out
__global__ void k_apply_f32(float* __restrict__ out, const float* __restrict__ statsG,
                            const float* __restrict__ gamma,
                            const float* __restrict__ beta) {
  __shared__ float ssc[256], ssh[256];
  const int t = threadIdx.x;    // 256
  {
    const float mean = statsG[t] * (1.f / 65536.f);
    const float var  = statsG[256 + t] * (1.f / 65536.f) - mean * mean;
    const float inv  = rsqrtf(var + 1e-5f);
    const float sc   = gamma[t] * inv;
    ssc[t] = sc;
    ssh[t] = beta[t] - mean * sc;
  }
  __syncthreads();
  float4* op = (float4*)out;
  for (size_t g = (size_t)blockIdx.x * 256 + t; g < 4194304ul; g += (size_t)gridDim.x * 256) {
    const int co = (int)((g >> 10) & 255);
    float4 y = op[g];
    const float sc = ssc[co], sh = ssh[co];
    y.x = y.x * sc + sh; y.y = y.y * sc + sh;
    y.z = y.z * sc + sh; y.w = y.w * sc + sh;
    op[g] = y;
  }
}

extern "C" void kernel_launch(void* const* d_in, const int* in_sizes, int n_in,
                              void* d_out, int out_size, void* d_ws, size_t ws_size,
                              hipStream_t stream) {
  const float* x     = (const float*)d_in[0];
  const float* wall  = (const float*)d_in[1];
  const float* bias  = (const float*)d_in[2];
  const float* alpha = (const float*)d_in[3];
  const float* gamma = (const float*)d_in[4];
  const float* beta  = (const float*)d_in[5];
  float* out = (float*)d_out;

  char* ws = (char*)d_ws;
  __bf16* xT     = (__bf16*)(ws + XT_OFF);
  __bf16* Wt     = (__bf16*)(ws + WT_OFF);
  float*  beff   = (float*)(ws + BEFF_OFF);
  float*  zerob  = (float*)(ws + ZERO_OFF);
  float*  statsG = (float*)(ws + STATS_OFF);
  __bf16* vbuf   = (__bf16*)(ws + V_OFF);
  const int use_v16 = (ws_size >= WS_NEED) ? 1 : 0;

  k_prep<<<1280, 256, 0, stream>>>(wall, bias, alpha, Wt, beff, zerob, statsG, x, xT);
  k_conv<<<512, 512, 0, stream>>>(x, xT, Wt, beff, (const __bf16*)zerob, out,
                                  statsG, vbuf, use_v16);
  if (use_v16)
    k_apply_v16<<<2048, 256, 0, stream>>>(vbuf, out, statsG, gamma, beta);
  else
    k_apply_f32<<<2048, 256, 0, stream>>>(out, statsG, gamma, beta);
}

// Round 16
// 116.296 us; speedup vs baseline: 1.0103x; 1.0103x over previous
//
#include <hip/hip_runtime.h>
#include <stdint.h>

typedef __attribute__((__ext_vector_type__(8))) __bf16 bf16x8;
typedef __attribute__((__ext_vector_type__(4))) float  f32x4;

// ---- workspace layout (bytes) ----
#define XT_OFF    0ul          // 16*64*64*256 bf16 = 33,554,432
#define WT_OFF    33554432ul   // 36*16384 bf16     =  1,179,648  [tap][s][co][ci64]
#define BEFF_OFF  34734080ul   // 256 f32
#define ZERO_OFF  34737152ul   // 256 B zeros
#define STATS_OFF 34737408ul   // 512 f32 (sum, sumsq per channel)
#define V_OFF     35651584ul   // 16M bf16 = 33,554,432 (v intermediate, NCHW)
#define WS_NEED   (V_OFF + 33554432ul)

__device__ inline void gload_lds16(const void* g, void* l) {
  __builtin_amdgcn_global_load_lds((const __attribute__((address_space(1))) void*)g,
                                   (__attribute__((address_space(3))) void*)l,
                                   16, 0, 0);
}

// K1 (merged): blocks 0..255 = weight reduction; 256..1279 = x transpose.
__global__ void k_prep(const float* __restrict__ w, const float* __restrict__ bias,
                       const float* __restrict__ alpha_p, __bf16* __restrict__ Wt,
                       float* __restrict__ beff, float* __restrict__ zerob,
                       float* __restrict__ statsG,
                       const float* __restrict__ x, __bf16* __restrict__ xT) {
  __shared__ __bf16 lds[64 * 258];
  if (blockIdx.x < 256) {
    const int co = blockIdx.x;
    const int ci = threadIdx.x;   // 256
    float a[9];
#pragma unroll
    for (int t = 0; t < 9; ++t) a[t] = 0.f;
#pragma unroll
    for (int r = 0; r < 2; ++r)
#pragma unroll
      for (int o = 0; o < 8; ++o) {
        const float* p = w + ((size_t)(r * 256 + co) * 2048 + (size_t)(o * 256 + ci)) * 9;
#pragma unroll
        for (int t = 0; t < 9; ++t) a[t] += p[t];
      }
    const float sc = alpha_p[0] * 0.0625f;      // alpha / (NORI*NROT)
    const int s = ci >> 6, cis = ci & 63;
#pragma unroll
    for (int t = 0; t < 9; ++t)
      Wt[(size_t)(t * 4 + s) * 16384 + co * 64 + cis] = (__bf16)(a[t] * sc);
    if (ci == 0) beff[co] = (bias[co] + bias[256 + co]) * 8.0f * sc;
    if (blockIdx.x == 0) {
      statsG[ci] = 0.f; statsG[256 + ci] = 0.f;
      if (ci < 64) zerob[ci] = 0.f;
    }
  } else {
    // ---- x[b][ci][h][w] f32 -> xT[b][h][w][ci] bf16 (LDS-tiled transpose)
    int bh = blockIdx.x - 256;    // 16*64
    int b = bh >> 6, h = bh & 63;
    int t = threadIdx.x;          // 256
    int w2 = t & 63, cg = t >> 6;
    const float* xb = x + ((size_t)b * 16384 + h) * 64;   // + ci*4096 + w
#pragma unroll 4
    for (int cb = 0; cb < 256; cb += 4) {
      int ci = cb + cg;
      lds[w2 * 258 + ci] = (__bf16)xb[(size_t)ci * 4096 + w2];
    }
    __syncthreads();
    const uint32_t* l32 = (const uint32_t*)lds;
    uint32_t* o32 = (uint32_t*)(xT + ((size_t)b * 64 + h) * 64 * 256);
    int c2 = t & 127, wg = t >> 7;              // 2 w per iter
    for (int w0 = 0; w0 < 64; w0 += 2) {
      int ww = w0 + wg;
      o32[ww * 128 + c2] = l32[ww * 129 + c2];
    }
  }
}

// K2: implicit-GEMM conv + residual + fused BN stats.
// R14 (measured best): TWO blocks per CU (decoupled barrier domains ->
// cross-block overlap of stage/drain with MFMA). 512 blocks of 512 thr
// (8 waves = 4m x 2n), block tile M=256 x N=128. Wave tile 64x64.
// LDS = A 51200 + B 16384 + lstat = 68.6 KB -> 2 blocks/CU.
// Per phase: [stageA if s-bound] stageB(p) -> vmcnt(0) -> bar -> MFMA -> bar.
// blockIdx encoding pairs co-halves on the same XCD slot: ch = (u>>3)&1.
#define A_BYTES 51200            // 50 chunks * 1024 (396 pos * 128B, padded)
#define B_BYTES 16384            // 128 co x 64 ci bf16

__global__ __launch_bounds__(512, 4) void k_conv(
    const float* __restrict__ x, const __bf16* __restrict__ xT,
    const __bf16* __restrict__ Wt, const float* __restrict__ beff,
    const __bf16* __restrict__ zerob, float* __restrict__ out,
    float* __restrict__ statsG, __bf16* __restrict__ vout, int use_v16)
{
  __shared__ __align__(16) char lds[A_BYTES + B_BYTES + 1024];   // 68608 B
  const int u    = blockIdx.x;               // 512 blocks
  const int ch   = (u >> 3) & 1;             // co half (pairs share XCD slot u&7)
  const int pairid = (u & 7) | ((u >> 4) << 3);   // 0..255
  const int bb   = pairid >> 4;              // batch
  const int ho0  = (pairid & 15) << 2;       // 4 output rows per block
  const int tid  = threadIdx.x;
  const int lane = tid & 63;
  const int wid  = tid >> 6;                 // 8 waves: 4 (m rows) x 2 (co 64s)
  const int wr   = wid >> 1;                 // image row ho0+wr
  const int wc   = wid & 1;                  // co quarter-of-half (64)
  const int l15  = lane & 15;

  f32x4 acc[4][4];
#pragma unroll
  for (int i = 0; i < 4; ++i)
#pragma unroll
    for (int j = 0; j < 4; ++j)
#pragma unroll
      for (int r = 0; r < 4; ++r) acc[i][j][r] = 0.f;

  const char* zb = (const char*)zerob;

  // hoisted B ds_read byte offsets within the 16KB tile (co_local 0..127)
  int boff[4][2];
#pragma unroll
  for (int j = 0; j < 4; ++j)
#pragma unroll
    for (int kk = 0; kk < 2; ++kk) {
      const int col    = (wc << 6) + (j << 4) + l15;      // 0..127
      const int ci_off = (kk << 5) + ((lane >> 4) << 3);
      boff[j][kk] = ((col << 7) + (ci_off << 1)) ^ ((col & 7) << 4);
    }
  // B stage per-lane source offset within the 16KB half-tile
  const int bl = lane >> 3;
  const int bsrcLane = (bl << 7) + (((lane & 7) ^ (bl & 7)) << 4);

  // ---- stage A slab for ci-block s: slab[r=6][c=66][ci=64] bf16, 128B/pos.
  // 16B-slot swizzle: phys = logical ^ (pos&7); linear dest + inverse-swz src.
  auto stageA = [&](int s) {
    const int ci0 = s << 6;
    for (int t = wid; t < 50; t += 8) {
      const int chk = (t << 3) + (lane >> 3);  // pos = r*66+c, 0..399
      const int r  = chk / 66;
      const int c  = chk - r * 66;
      const int ir = ho0 - 1 + r;              // image row
      const int ic = c - 1;                    // image col
      const int k  = (lane & 7) ^ (chk & 7);   // logical 16B slot (8 ci elems)
      const char* src;
      if (chk < 396 && ir >= 0 && ir < 64 && ic >= 0 && ic < 64)
        src = (const char*)(xT + ((((size_t)bb << 6) + ir) * 64 + ic) * 256 + ci0 + (k << 3));
      else
        src = zb + (k << 4);
      gload_lds16(src, lds + (t << 10));
    }
  };

  // ---- stage B half-tile for flat phase ph (2 loads per wave, 16 chunks)
  auto stageB = [&](int ph) {
    char* buf = lds + A_BYTES;
    const int s2 = ph / 9, tp = ph - s2 * 9;
    const char* wsrc = (const char*)Wt + ((size_t)(tp * 4 + s2) << 15) + (ch << 14) + bsrcLane;
    gload_lds16(wsrc + (wid << 10), buf + (wid << 10));
    gload_lds16(wsrc + ((wid + 8) << 10), buf + ((wid + 8) << 10));
  };

  int s = 0, tap = 0;
  for (int p = 0; p < 36; ++p) {
    if (tap == 0) stageA(s);                   // p=0 initial; else slab free (end-bar)
    stageB(p);
    asm volatile("s_waitcnt vmcnt(0)" ::: "memory");
    __builtin_amdgcn_s_barrier();              // all waves' stages landed
    asm volatile("" ::: "memory");

    const int dh = (tap >= 6) ? 2 : (tap >= 3 ? 1 : 0);
    const int dw = tap - dh * 3;
    const char* Bb = lds + A_BYTES;
    __builtin_amdgcn_s_setprio(1);
#pragma unroll
    for (int kk = 0; kk < 2; ++kk) {
      const int ci_off = (kk << 5) + ((lane >> 4) << 3);
      bf16x8 av[4];
#pragma unroll
      for (int i = 0; i < 4; ++i) {
        const int pos = (wr + dh) * 66 + (i << 4) + l15 + dw;
        const int off = ((pos << 7) + (ci_off << 1)) ^ ((pos & 7) << 4);
        av[i] = *(const bf16x8*)(lds + off);
      }
#pragma unroll
      for (int j = 0; j < 4; ++j) {
        const bf16x8 bv = *(const bf16x8*)(Bb + boff[j][kk]);
#pragma unroll
        for (int i = 0; i < 4; ++i)
          acc[i][j] = __builtin_amdgcn_mfma_f32_16x16x32_bf16(av[i], bv, acc[i][j], 0, 0, 0);
      }
    }
    __builtin_amdgcn_s_setprio(0);
    asm volatile("" ::: "memory");
    __builtin_amdgcn_s_barrier();              // readers done -> slot/slab reusable
    asm volatile("" ::: "memory");

    if (++tap == 9) { tap = 0; ++s; }
  }

  // ---- epilogue: v = x+conv+beff, stats in-reg (f32), bf16 v via per-wave
  // LDS repack -> full-line 16B/lane stores (use_v16), else f32 to out.
  __syncthreads();
  float* lstat = (float*)(lds + A_BYTES + B_BYTES);   // 256 floats (sum128, sq128)
  if (tid < 256) lstat[tid] = 0.f;
  __syncthreads();

  char* wreg = lds + wid * 2048;               // this wave's repack region (16KB tot)
  const int wq = lane >> 4;                    // 0..3 (w quad group)
  const int ho = ho0 + wr;
  const int xorco = (l15 & 7) << 4;
#pragma unroll
  for (int j = 0; j < 4; ++j) {
    const int col = (wc << 6) + (j << 4) + l15;         // co_local 0..127
    const int cog = (ch << 7) + col;                    // global co
    const float be = beff[cog];
    const size_t base = ((((size_t)bb << 8) + (size_t)cog) << 12) + (ho << 6);
    float r1 = 0.f, r2 = 0.f;
#pragma unroll
    for (int i = 0; i < 4; ++i) {
      const int w0 = (i << 4) + (wq << 2);
      const float4 xv = *(const float4*)(x + base + w0);
      float4 v;
      v.x = acc[i][j][0] + xv.x + be;
      v.y = acc[i][j][1] + xv.y + be;
      v.z = acc[i][j][2] + xv.z + be;
      v.w = acc[i][j][3] + xv.w + be;
      r1 += v.x + v.y + v.z + v.w;
      r2 += v.x * v.x + v.y * v.y + v.z * v.z + v.w * v.w;
      if (use_v16) {
        union { __bf16 h[4]; uint64_t u64; } pk;
        pk.h[0] = (__bf16)v.x; pk.h[1] = (__bf16)v.y;
        pk.h[2] = (__bf16)v.z; pk.h[3] = (__bf16)v.w;
        const int wa = (l15 << 7) + (i << 5) + (wq << 3);
        *(uint64_t*)(wreg + (wa ^ xorco)) = pk.u64;
      } else {
        *(float4*)(out + base + w0) = v;
      }
    }
    r1 += __shfl_xor(r1, 16); r2 += __shfl_xor(r2, 16);
    r1 += __shfl_xor(r1, 32); r2 += __shfl_xor(r2, 32);
    if (lane < 16) {
      atomicAdd(&lstat[col], r1);
      atomicAdd(&lstat[128 + col], r2);
    }
    if (use_v16) {
      asm volatile("s_waitcnt lgkmcnt(0)" ::: "memory");   // wave's writes visible
#pragma unroll
      for (int t2 = 0; t2 < 2; ++t2) {
        const int co_r = lane >> 2;              // 0..15
        const int chk  = (lane & 3) + (t2 << 2); // 16B chunk = 8 w
        const int ra   = (co_r << 7) + (chk << 4);
        const uint4 pv = *(const uint4*)(wreg + (ra ^ ((co_r & 7) << 4)));
        const int co_g = (ch << 7) + (wc << 6) + (j << 4) + co_r;
        const size_t oi = ((((size_t)bb << 8) + (size_t)co_g) << 12) + (ho << 6) + (chk << 3);
        *(uint4*)(vout + oi) = pv;               // 16B x 4 lanes/co -> 64B lines
      }
      asm volatile("s_waitcnt lgkmcnt(0)" ::: "memory");   // reads done before next j
    }
  }
  __syncthreads();
  if (tid < 256) {
    const int c = tid & 127, part = tid >> 7;
    atomicAdd(&statsG[part * 256 + (ch << 7) + c], lstat[part * 128 + c]);
  }
}

// K3a: BN finalize + apply from bf16 v (NCHW) -> f32 out (grid-stride)
__global__ void k_apply_v16(const __bf16* __restrict__ v, float* __restrict__ out,
                            const float* __restrict__ statsG,
                            const float* __restrict__ gamma,
                            const float* __restrict__ beta) {
  __shared__ float ssc[256], ssh[256];
  const int t = threadIdx.x;    // 256
  {
    const float mean = statsG[t] * (1.f / 65536.f);
    const float var  = statsG[256 + t] * (1.f / 65536.f) - mean * mean;
    const float inv  = rsqrtf(var + 1e-5f);
    const float sc   = gamma[t] * inv;
    ssc[t] = sc;
    ssh[t] = beta[t] - mean * sc;
  }
  __syncthreads();
  const uint4* vp = (const uint4*)v;           // 8 bf16 per uint4
  for (size_t g = (size_t)blockIdx.x * 256 + t; g < 2097152ul; g += (size_t)gridDim.x * 256) {
    const int co = (int)((g >> 9) & 255);      // 512 chunks of 8 per (b,co) plane
    const uint4 pv = vp[g];
    const float sc = ssc[co], sh = ssh[co];
    float4 y0, y1;
    y0.x = __uint_as_float((pv.x & 0xffffu) << 16) * sc + sh;
    y0.y = __uint_as_float(pv.x & 0xffff0000u) * sc + sh;
    y0.z = __uint_as_float((pv.y & 0xffffu) << 16) * sc + sh;
    y0.w = __uint_as_float(pv.y & 0xffff0000u) * sc + sh;
    y1.x = __uint_as_float((pv.z & 0xffffu) << 16) * sc + sh;
    y1.y = __uint_as_float(pv.z & 0xffff0000u) * sc + sh;
    y1.z = __uint_as_float((pv.w & 0xffffu) << 16) * sc + sh;
    y1.w = __uint_as_float(pv.w & 0xffff0000u) * sc + sh;
    float4* op = (float4*)(out + g * 8);
    op[0] = y0;
    op[1] = y1;
  }
}

// K3b: fallback — BN finalize + in-place apply on f32 out
__global__ void k_apply_f32(float* __restrict__ out, const float* __restrict__ statsG,
                            const float* __restrict__ gamma,
                            const float* __restrict__ beta) {
  __shared__ float ssc[256], ssh[256];
  const int t = threadIdx.x;    // 256
  {
    const float mean = statsG[t] * (1.f / 65536.f);
    const float var  = statsG[256 + t] * (1.f / 65536.f) - mean * mean;
    const float inv  = rsqrtf(var + 1e-5f);
    const float sc   = gamma[t] * inv;
    ssc[t] = sc;
    ssh[t] = beta[t] - mean * sc;
  }
  __syncthreads();
  float4* op = (float4*)out;
  for (size_t g = (size_t)blockIdx.x * 256 + t; g < 4194304ul; g += (size_t)gridDim.x * 256) {
    const int co = (int)((g >> 10) & 255);
    float4 y = op[g];
    const float sc = ssc[co], sh = ssh[co];
    y.x = y.x * sc + sh; y.y = y.y * sc + sh;
    y.z = y.z * sc + sh; y.w = y.w * sc + sh;
    op[g] = y;
  }
}

extern "C" void kernel_launch(void* const* d_in, const int* in_sizes, int n_in,
                              void* d_out, int out_size, void* d_ws, size_t ws_size,
                              hipStream_t stream) {
  const float* x     = (const float*)d_in[0];
  const float* wall  = (const float*)d_in[1];
  const float* bias  = (const float*)d_in[2];
  const float* alpha = (const float*)d_in[3];
  const float* gamma = (const float*)d_in[4];
  const float* beta  = (const float*)d_in[5];
  float* out = (float*)d_out;

  char* ws = (char*)d_ws;
  __bf16* xT     = (__bf16*)(ws + XT_OFF);
  __bf16* Wt     = (__bf16*)(ws + WT_OFF);
  float*  beff   = (float*)(ws + BEFF_OFF);
  float*  zerob  = (float*)(ws + ZERO_OFF);
  float*  statsG = (float*)(ws + STATS_OFF);
  __bf16* vbuf   = (__bf16*)(ws + V_OFF);
  const int use_v16 = (ws_size >= WS_NEED) ? 1 : 0;

  k_prep<<<1280, 256, 0, stream>>>(wall, bias, alpha, Wt, beff, zerob, statsG, x, xT);
  k_conv<<<512, 512, 0, stream>>>(x, xT, Wt, beff, (const __bf16*)zerob, out,
                                  statsG, vbuf, use_v16);
  if (use_v16)
    k_apply_v16<<<2048, 256, 0, stream>>>(vbuf, out, statsG, gamma, beta);
  else
    k_apply_f32<<<2048, 256, 0, stream>>>(out, statsG, gamma, beta);
}

// Round 17
// 108.079 us; speedup vs baseline: 1.0871x; 1.0760x over previous
//
#include <hip/hip_runtime.h>
#include <stdint.h>

typedef __attribute__((__ext_vector_type__(8))) __bf16 bf16x8;
typedef __attribute__((__ext_vector_type__(4))) float  f32x4;

// ---- workspace layout (bytes) ----
#define XT_OFF    0ul          // 16*64*64*256 bf16 = 33,554,432
#define WT_OFF    33554432ul   // 36*16384 bf16     =  1,179,648  [tap][s][co][ci64]
#define BEFF_OFF  34734080ul   // 256 f32
#define ZERO_OFF  34737152ul   // 256 B zeros
#define STATS_OFF 34737408ul   // 512 f32 (sum, sumsq per channel)
#define V_OFF     35651584ul   // 16M bf16 = 33,554,432 (v intermediate, NCHW)
#define WS_NEED   (V_OFF + 33554432ul)

__device__ inline void gload_lds16(const void* g, void* l) {
  __builtin_amdgcn_global_load_lds((const __attribute__((address_space(1))) void*)g,
                                   (__attribute__((address_space(3))) void*)l,
                                   16, 0, 0);
}

// K1 (merged): blocks 0..255 = weight reduction; 256..1279 = x transpose.
// R17: residual folded into the conv — center tap (tap==4) gets +1.0 on the
// diagonal (ci==co), so v = conv'(x) + beff needs NO x re-read in the epilogue.
__global__ void k_prep(const float* __restrict__ w, const float* __restrict__ bias,
                       const float* __restrict__ alpha_p, __bf16* __restrict__ Wt,
                       float* __restrict__ beff, float* __restrict__ zerob,
                       float* __restrict__ statsG,
                       const float* __restrict__ x, __bf16* __restrict__ xT) {
  __shared__ __bf16 lds[64 * 258];
  if (blockIdx.x < 256) {
    const int co = blockIdx.x;
    const int ci = threadIdx.x;   // 256
    float a[9];
#pragma unroll
    for (int t = 0; t < 9; ++t) a[t] = 0.f;
#pragma unroll
    for (int r = 0; r < 2; ++r)
#pragma unroll
      for (int o = 0; o < 8; ++o) {
        const float* p = w + ((size_t)(r * 256 + co) * 2048 + (size_t)(o * 256 + ci)) * 9;
#pragma unroll
        for (int t = 0; t < 9; ++t) a[t] += p[t];
      }
    const float sc = alpha_p[0] * 0.0625f;      // alpha / (NORI*NROT)
    const int s = ci >> 6, cis = ci & 63;
#pragma unroll
    for (int t = 0; t < 9; ++t) {
      float val = a[t] * sc;
      if (t == 4 && ci == co) val += 1.0f;      // identity: residual in-conv
      Wt[(size_t)(t * 4 + s) * 16384 + co * 64 + cis] = (__bf16)val;
    }
    if (ci == 0) beff[co] = (bias[co] + bias[256 + co]) * 8.0f * sc;
    if (blockIdx.x == 0) {
      statsG[ci] = 0.f; statsG[256 + ci] = 0.f;
      if (ci < 64) zerob[ci] = 0.f;
    }
  } else {
    // ---- x[b][ci][h][w] f32 -> xT[b][h][w][ci] bf16 (LDS-tiled transpose)
    int bh = blockIdx.x - 256;    // 16*64
    int b = bh >> 6, h = bh & 63;
    int t = threadIdx.x;          // 256
    int w2 = t & 63, cg = t >> 6;
    const float* xb = x + ((size_t)b * 16384 + h) * 64;   // + ci*4096 + w
#pragma unroll 4
    for (int cb = 0; cb < 256; cb += 4) {
      int ci = cb + cg;
      lds[w2 * 258 + ci] = (__bf16)xb[(size_t)ci * 4096 + w2];
    }
    __syncthreads();
    const uint32_t* l32 = (const uint32_t*)lds;
    uint32_t* o32 = (uint32_t*)(xT + ((size_t)b * 64 + h) * 64 * 256);
    int c2 = t & 127, wg = t >> 7;              // 2 w per iter
    for (int w0 = 0; w0 < 64; w0 += 2) {
      int ww = w0 + wg;
      o32[ww * 128 + c2] = l32[ww * 129 + c2];
    }
  }
}

// K2: implicit-GEMM conv (+folded residual) + fused BN stats.
// R14 structure (measured best): TWO blocks per CU (decoupled barrier domains
// -> cross-block overlap of stage/drain with MFMA). 512 blocks of 512 thr
// (8 waves = 4m x 2n), block tile M=256 x N=128. Wave tile 64x64.
// LDS = A 51200 + B 16384 + lstat = 68.6 KB -> 2 blocks/CU.
// Per phase: [stageA if s-bound] stageB(p) -> vmcnt(0) -> bar -> MFMA -> bar.
// Epilogue: v = acc + beff (NO x read — residual folded into Wt), stats
// in-register, bf16 v via per-wave LDS repack -> full 64B-line stores.
#define A_BYTES 51200            // 50 chunks * 1024 (396 pos * 128B, padded)
#define B_BYTES 16384            // 128 co x 64 ci bf16

__global__ __launch_bounds__(512, 4) void k_conv(
    const float* __restrict__ x, const __bf16* __restrict__ xT,
    const __bf16* __restrict__ Wt, const float* __restrict__ beff,
    const __bf16* __restrict__ zerob, float* __restrict__ out,
    float* __restrict__ statsG, __bf16* __restrict__ vout, int use_v16)
{
  __shared__ __align__(16) char lds[A_BYTES + B_BYTES + 1024];   // 68608 B
  const int u    = blockIdx.x;               // 512 blocks
  const int ch   = (u >> 3) & 1;             // co half (pairs share XCD slot u&7)
  const int pairid = (u & 7) | ((u >> 4) << 3);   // 0..255
  const int bb   = pairid >> 4;              // batch
  const int ho0  = (pairid & 15) << 2;       // 4 output rows per block
  const int tid  = threadIdx.x;
  const int lane = tid & 63;
  const int wid  = tid >> 6;                 // 8 waves: 4 (m rows) x 2 (co 64s)
  const int wr   = wid >> 1;                 // image row ho0+wr
  const int wc   = wid & 1;                  // co quarter-of-half (64)
  const int l15  = lane & 15;

  f32x4 acc[4][4];
#pragma unroll
  for (int i = 0; i < 4; ++i)
#pragma unroll
    for (int j = 0; j < 4; ++j)
#pragma unroll
      for (int r = 0; r < 4; ++r) acc[i][j][r] = 0.f;

  const char* zb = (const char*)zerob;

  // hoisted B ds_read byte offsets within the 16KB tile (co_local 0..127)
  int boff[4][2];
#pragma unroll
  for (int j = 0; j < 4; ++j)
#pragma unroll
    for (int kk = 0; kk < 2; ++kk) {
      const int col    = (wc << 6) + (j << 4) + l15;      // 0..127
      const int ci_off = (kk << 5) + ((lane >> 4) << 3);
      boff[j][kk] = ((col << 7) + (ci_off << 1)) ^ ((col & 7) << 4);
    }
  // B stage per-lane source offset within the 16KB half-tile
  const int bl = lane >> 3;
  const int bsrcLane = (bl << 7) + (((lane & 7) ^ (bl & 7)) << 4);

  // ---- stage A slab for ci-block s: slab[r=6][c=66][ci=64] bf16, 128B/pos.
  // 16B-slot swizzle: phys = logical ^ (pos&7); linear dest + inverse-swz src.
  auto stageA = [&](int s) {
    const int ci0 = s << 6;
    for (int t = wid; t < 50; t += 8) {
      const int chk = (t << 3) + (lane >> 3);  // pos = r*66+c, 0..399
      const int r  = chk / 66;
      const int c  = chk - r * 66;
      const int ir = ho0 - 1 + r;              // image row
      const int ic = c - 1;                    // image col
      const int k  = (lane & 7) ^ (chk & 7);   // logical 16B slot (8 ci elems)
      const char* src;
      if (chk < 396 && ir >= 0 && ir < 64 && ic >= 0 && ic < 64)
        src = (const char*)(xT + ((((size_t)bb << 6) + ir) * 64 + ic) * 256 + ci0 + (k << 3));
      else
        src = zb + (k << 4);
      gload_lds16(src, lds + (t << 10));
    }
  };

  // ---- stage B half-tile for flat phase ph (2 loads per wave, 16 chunks)
  auto stageB = [&](int ph) {
    char* buf = lds + A_BYTES;
    const int s2 = ph / 9, tp = ph - s2 * 9;
    const char* wsrc = (const char*)Wt + ((size_t)(tp * 4 + s2) << 15) + (ch << 14) + bsrcLane;
    gload_lds16(wsrc + (wid << 10), buf + (wid << 10));
    gload_lds16(wsrc + ((wid + 8) << 10), buf + ((wid + 8) << 10));
  };

  int s = 0, tap = 0;
  for (int p = 0; p < 36; ++p) {
    if (tap == 0) stageA(s);                   // p=0 initial; else slab free (end-bar)
    stageB(p);
    asm volatile("s_waitcnt vmcnt(0)" ::: "memory");
    __builtin_amdgcn_s_barrier();              // all waves' stages landed
    asm volatile("" ::: "memory");

    const int dh = (tap >= 6) ? 2 : (tap >= 3 ? 1 : 0);
    const int dw = tap - dh * 3;
    const char* Bb = lds + A_BYTES;
    __builtin_amdgcn_s_setprio(1);
#pragma unroll
    for (int kk = 0; kk < 2; ++kk) {
      const int ci_off = (kk << 5) + ((lane >> 4) << 3);
      bf16x8 av[4];
#pragma unroll
      for (int i = 0; i < 4; ++i) {
        const int pos = (wr + dh) * 66 + (i << 4) + l15 + dw;
        const int off = ((pos << 7) + (ci_off << 1)) ^ ((pos & 7) << 4);
        av[i] = *(const bf16x8*)(lds + off);
      }
#pragma unroll
      for (int j = 0; j < 4; ++j) {
        const bf16x8 bv = *(const bf16x8*)(Bb + boff[j][kk]);
#pragma unroll
        for (int i = 0; i < 4; ++i)
          acc[i][j] = __builtin_amdgcn_mfma_f32_16x16x32_bf16(av[i], bv, acc[i][j], 0, 0, 0);
      }
    }
    __builtin_amdgcn_s_setprio(0);
    asm volatile("" ::: "memory");
    __builtin_amdgcn_s_barrier();              // readers done -> slot/slab reusable
    asm volatile("" ::: "memory");

    if (++tap == 9) { tap = 0; ++s; }
  }

  // ---- epilogue: v = acc + beff (residual already in conv), in-reg stats,
  // bf16 v via per-wave LDS repack -> full-line 16B/lane stores.
  __syncthreads();
  float* lstat = (float*)(lds + A_BYTES + B_BYTES);   // 256 floats (sum128, sq128)
  if (tid < 256) lstat[tid] = 0.f;
  __syncthreads();

  char* wreg = lds + wid * 2048;               // this wave's repack region (16KB tot)
  const int wq = lane >> 4;                    // 0..3 (w quad group)
  const int ho = ho0 + wr;
  const int xorco = (l15 & 7) << 4;
#pragma unroll
  for (int j = 0; j < 4; ++j) {
    const int col = (wc << 6) + (j << 4) + l15;         // co_local 0..127
    const int cog = (ch << 7) + col;                    // global co
    const float be = beff[cog];
    const size_t base = ((((size_t)bb << 8) + (size_t)cog) << 12) + (ho << 6);
    float r1 = 0.f, r2 = 0.f;
#pragma unroll
    for (int i = 0; i < 4; ++i) {
      const int w0 = (i << 4) + (wq << 2);
      float4 v;
      v.x = acc[i][j][0] + be;
      v.y = acc[i][j][1] + be;
      v.z = acc[i][j][2] + be;
      v.w = acc[i][j][3] + be;
      r1 += v.x + v.y + v.z + v.w;
      r2 += v.x * v.x + v.y * v.y + v.z * v.z + v.w * v.w;
      if (use_v16) {
        union { __bf16 h[4]; uint64_t u64; } pk;
        pk.h[0] = (__bf16)v.x; pk.h[1] = (__bf16)v.y;
        pk.h[2] = (__bf16)v.z; pk.h[3] = (__bf16)v.w;
        const int wa = (l15 << 7) + (i << 5) + (wq << 3);
        *(uint64_t*)(wreg + (wa ^ xorco)) = pk.u64;
      } else {
        *(float4*)(out + base + w0) = v;
      }
    }
    r1 += __shfl_xor(r1, 16); r2 += __shfl_xor(r2, 16);
    r1 += __shfl_xor(r1, 32); r2 += __shfl_xor(r2, 32);
    if (lane < 16) {
      atomicAdd(&lstat[col], r1);
      atomicAdd(&lstat[128 + col], r2);
    }
    if (use_v16) {
      asm volatile("s_waitcnt lgkmcnt(0)" ::: "memory");   // wave's writes visible
#pragma unroll
      for (int t2 = 0; t2 < 2; ++t2) {
        const int co_r = lane >> 2;              // 0..15
        const int chk  = (lane & 3) + (t2 << 2); // 16B chunk = 8 w
        const int ra   = (co_r << 7) + (chk << 4);
        const uint4 pv = *(const uint4*)(wreg + (ra ^ ((co_r & 7) << 4)));
        const int co_g = (ch << 7) + (wc << 6) + (j << 4) + co_r;
        const size_t oi = ((((size_t)bb << 8) + (size_t)co_g) << 12) + (ho << 6) + (chk << 3);
        *(uint4*)(vout + oi) = pv;               // 16B x 4 lanes/co -> 64B lines
      }
      asm volatile("s_waitcnt lgkmcnt(0)" ::: "memory");   // reads done before next j
    }
  }
  __syncthreads();
  if (tid < 256) {
    const int c = tid & 127, part = tid >> 7;
    atomicAdd(&statsG[part * 256 + (ch << 7) + c], lstat[part * 128 + c]);
  }
}

// K3a: BN finalize + apply from bf16 v (NCHW) -> f32 out (grid-stride)
__global__ void k_apply_v16(const __bf16* __restrict__ v, float* __restrict__ out,
                            const float* __restrict__ statsG,
                            const float* __restrict__ gamma,
                            const float* __restrict__ beta) {
  __shared__ float ssc[256], ssh[256];
  const int t = threadIdx.x;    // 256
  {
    const float mean = statsG[t] * (1.f / 65536.f);
    const float var  = statsG[256 + t] * (1.f / 65536.f) - mean * mean;
    const float inv  = rsqrtf(var + 1e-5f);
    const float sc   = gamma[t] * inv;
    ssc[t] = sc;
    ssh[t] = beta[t] - mean * sc;
  }
  __syncthreads();
  const uint4* vp = (const uint4*)v;           // 8 bf16 per uint4
  for (size_t g = (size_t)blockIdx.x * 256 + t; g < 2097152ul; g += (size_t)gridDim.x * 256) {
    const int co = (int)((g >> 9) & 255);      // 512 chunks of 8 per (b,co) plane
    const uint4 pv = vp[g];
    const float sc = ssc[co], sh = ssh[co];
    float4 y0, y1;
    y0.x = __uint_as_float((pv.x & 0xffffu) << 16) * sc + sh;
    y0.y = __uint_as_float(pv.x & 0xffff0000u) * sc + sh;
    y0.z = __uint_as_float((pv.y & 0xffffu) << 16) * sc + sh;
    y0.w = __uint_as_float(pv.y & 0xffff0000u) * sc + sh;
    y1.x = __uint_as_float((pv.z & 0xffffu) << 16) * sc + sh;
    y1.y = __uint_as_float(pv.z & 0xffff0000u) * sc + sh;
    y1.z = __uint_as_float((pv.w & 0xffffu) << 16) * sc + sh;
    y1.w = __uint_as_float(pv.w & 0xffff0000u) * sc + sh;
    float4* op = (float4*)(out + g * 8);
    op[0] = y0;
    op[1] = y1;
  }
}

// K3b: fallback — BN finalize + in-place apply on f32 out
__global__ void k_apply_f32(float* __restrict__ out, const float* __restrict__ statsG,
                            const float* __restrict__ gamma,
                            const float* __restrict__ beta) {
  __shared__ float ssc[256], ssh[256];
  const int t = threadIdx.x;    // 256
  {
    const float mean = statsG[t] * (1.f / 65536.f);
    const float var  = statsG[256 + t] * (1.f / 65536.f) - mean * mean;
    const float inv  = rsqrtf(var + 1e-5f);
    const float sc   = gamma[t] * inv;
    ssc[t] = sc;
    ssh[t] = beta[t] - mean * sc;
  }
  __syncthreads();
  float4* op = (float4*)out;
  for (size_t g = (size_t)blockIdx.x * 256 + t; g < 4194304ul; g += (size_t)gridDim.x * 256) {
    const int co = (int)((g >> 10) & 255);
    float4 y = op[g];
    const float sc = ssc[co], sh = ssh[co];
    y.x = y.x * sc + sh; y.y = y.y * sc + sh;
    y.z = y.z * sc + sh; y.w = y.w * sc + sh;
    op[g] = y;
  }
}

extern "C" void kernel_launch(void* const* d_in, const int* in_sizes, int n_in,
                              void* d_out, int out_size, void* d_ws, size_t ws_size,
                              hipStream_t stream) {
  const float* x     = (const float*)d_in[0];
  const float* wall  = (const float*)d_in[1];
  const float* bias  = (const float*)d_in[2];
  const float* alpha = (const float*)d_in[3];
  const float* gamma = (const float*)d_in[4];
  const float* beta  = (const float*)d_in[5];
  float* out = (float*)d_out;

  char* ws = (char*)d_ws;
  __bf16* xT     = (__bf16*)(ws + XT_OFF);
  __bf16* Wt     = (__bf16*)(ws + WT_OFF);
  float*  beff   = (float*)(ws + BEFF_OFF);
  float*  zerob  = (float*)(ws + ZERO_OFF);
  float*  statsG = (float*)(ws + STATS_OFF);
  __bf16* vbuf   = (__bf16*)(ws + V_OFF);
  const int use_v16 = (ws_size >= WS_NEED) ? 1 : 0;

  k_prep<<<1280, 256, 0, stream>>>(wall, bias, alpha, Wt, beff, zerob, statsG, x, xT);
  k_conv<<<512, 512, 0, stream>>>(x, xT, Wt, beff, (const __bf16*)zerob, out,
                                  statsG, vbuf, use_v16);
  if (use_v16)
    k_apply_v16<<<2048, 256, 0, stream>>>(vbuf, out, statsG, gamma, beta);
  else
    k_apply_f32<<<2048, 256, 0, stream>>>(out, statsG, gamma, beta);
}